// Round 2
// baseline (441.325 us; speedup 1.0000x reference)
//
#include <hip/hip_runtime.h>

// L2Q attention, fp16-MFMA with hi/lo split on the q/k precision chain.
// B=8, N=1024, C=768, H=12, d=64, 3C=2304, M=B*N=8192.

typedef _Float16 f16x8 __attribute__((ext_vector_type(8)));
typedef _Float16 f16x4 __attribute__((ext_vector_type(4)));
typedef float f32x4 __attribute__((ext_vector_type(4)));

#define NB 8
#define NN 1024
#define NC 768
#define NH 12
#define ND 64
#define TC 2304
#define NM 8192

// ---------------- fp32 -> fp16 convert (single) ----------------
__global__ void cvt_f32_f16(const float* __restrict__ s, _Float16* __restrict__ d, int n4) {
    int i = blockIdx.x * 256 + threadIdx.x;
    if (i < n4) {
        float4 v = ((const float4*)s)[i];
        f16x4 o;
        o[0] = (_Float16)v.x; o[1] = (_Float16)v.y;
        o[2] = (_Float16)v.z; o[3] = (_Float16)v.w;
        ((f16x4*)d)[i] = o;
    }
}

// ---------------- fp32 -> fp16 hi/lo split ----------------
__global__ void cvt_split_f32(const float* __restrict__ s, _Float16* __restrict__ hi,
                              _Float16* __restrict__ lo, int n4) {
    int i = blockIdx.x * 256 + threadIdx.x;
    if (i < n4) {
        float4 v = ((const float4*)s)[i];
        f16x4 h, l;
        h[0] = (_Float16)v.x; l[0] = (_Float16)(v.x - (float)h[0]);
        h[1] = (_Float16)v.y; l[1] = (_Float16)(v.y - (float)h[1]);
        h[2] = (_Float16)v.z; l[2] = (_Float16)(v.z - (float)h[2]);
        h[3] = (_Float16)v.w; l[3] = (_Float16)(v.w - (float)h[3]);
        ((f16x4*)hi)[i] = h;
        ((f16x4*)lo)[i] = l;
    }
}

// ---------------- qkv GEMM (split precision): C[8192,2304] = X * Wqkv^T ----------------
// A staged from fp32 X, split hi/lo on the fly. 3-term MFMA: ah*bh + al*bh + ah*bl.
// grid (64 mtiles, 18 ntiles), 256 threads (4 waves, 2x2 wave grid).
__global__ __launch_bounds__(256) void gemm_qkv(
    const float* __restrict__ X, const _Float16* __restrict__ Bh, const _Float16* __restrict__ Bl,
    _Float16* __restrict__ qh, _Float16* __restrict__ ql,
    _Float16* __restrict__ kh, _Float16* __restrict__ kl,
    _Float16* __restrict__ vt16)
{
    __shared__ __align__(16) _Float16 sAh[128 * 32];
    __shared__ __align__(16) _Float16 sAl[128 * 32];
    __shared__ __align__(16) _Float16 sBh[128 * 32];
    __shared__ __align__(16) _Float16 sBl[128 * 32];
    const int tid = threadIdx.x;
    const int lane = tid & 63, wv = tid >> 6;
    const int quad = lane >> 4, l16 = lane & 15;
    const int wm = (wv >> 1) * 64, wn = (wv & 1) * 64;
    const int m0 = blockIdx.x * 128, n0 = blockIdx.y * 128;

    f32x4 acc[4][4] = {};

    for (int k0 = 0; k0 < NC; k0 += 32) {
#pragma unroll
        for (int i = 0; i < 2; i++) {
            int c = tid + i * 256;       // chunk 0..511
            int r = c >> 2, kc = c & 3;  // row, 8-elem chunk within row
            const float4* pa = (const float4*)(X + (size_t)(m0 + r) * NC + k0 + kc * 8);
            float4 v0 = pa[0], v1 = pa[1];
            f16x8 hi8, lo8;
            hi8[0] = (_Float16)v0.x; lo8[0] = (_Float16)(v0.x - (float)hi8[0]);
            hi8[1] = (_Float16)v0.y; lo8[1] = (_Float16)(v0.y - (float)hi8[1]);
            hi8[2] = (_Float16)v0.z; lo8[2] = (_Float16)(v0.z - (float)hi8[2]);
            hi8[3] = (_Float16)v0.w; lo8[3] = (_Float16)(v0.w - (float)hi8[3]);
            hi8[4] = (_Float16)v1.x; lo8[4] = (_Float16)(v1.x - (float)hi8[4]);
            hi8[5] = (_Float16)v1.y; lo8[5] = (_Float16)(v1.y - (float)hi8[5]);
            hi8[6] = (_Float16)v1.z; lo8[6] = (_Float16)(v1.z - (float)hi8[6]);
            hi8[7] = (_Float16)v1.w; lo8[7] = (_Float16)(v1.w - (float)hi8[7]);
            *(f16x8*)(sAh + c * 8) = hi8;
            *(f16x8*)(sAl + c * 8) = lo8;
            uint4 vbh = *(const uint4*)(Bh + (size_t)(n0 + r) * NC + k0 + kc * 8);
            *(uint4*)(sBh + c * 8) = vbh;
            uint4 vbl = *(const uint4*)(Bl + (size_t)(n0 + r) * NC + k0 + kc * 8);
            *(uint4*)(sBl + c * 8) = vbl;
        }
        __syncthreads();
        f16x8 ah[4], al[4], bh[4], bl[4];
#pragma unroll
        for (int t = 0; t < 4; t++) {
            ah[t] = *(const f16x8*)(sAh + (wm + t * 16 + l16) * 32 + quad * 8);
            al[t] = *(const f16x8*)(sAl + (wm + t * 16 + l16) * 32 + quad * 8);
            bh[t] = *(const f16x8*)(sBh + (wn + t * 16 + l16) * 32 + quad * 8);
            bl[t] = *(const f16x8*)(sBl + (wn + t * 16 + l16) * 32 + quad * 8);
        }
#pragma unroll
        for (int i = 0; i < 4; i++)
#pragma unroll
            for (int j = 0; j < 4; j++) {
                acc[i][j] = __builtin_amdgcn_mfma_f32_16x16x32_f16(ah[i], bh[j], acc[i][j], 0, 0, 0);
                acc[i][j] = __builtin_amdgcn_mfma_f32_16x16x32_f16(al[i], bh[j], acc[i][j], 0, 0, 0);
                acc[i][j] = __builtin_amdgcn_mfma_f32_16x16x32_f16(ah[i], bl[j], acc[i][j], 0, 0, 0);
            }
        __syncthreads();
    }

    // epilogue: q,k as hi/lo pairs [B,H,N,d]; v^T fp16 [B,H,d,N]
#pragma unroll
    for (int i = 0; i < 4; i++) {
#pragma unroll
        for (int j = 0; j < 4; j++) {
#pragma unroll
            for (int r = 0; r < 4; r++) {
                int row = m0 + wm + i * 16 + quad * 4 + r;   // global m
                int col = n0 + wn + j * 16 + l16;            // global col in [0,2304)
                float fv = acc[i][j][r];
                int b = row >> 10, nr = row & 1023;
                int which = col / NC;
                int w2 = col - which * NC;
                int h = w2 >> 6, dd = w2 & 63;
                int bhd = b * NH + h;
                size_t idx = ((size_t)(bhd * NN + nr)) * ND + dd;
                if (which == 0) {
                    _Float16 hv = (_Float16)fv;
                    qh[idx] = hv;
                    ql[idx] = (_Float16)(fv - (float)hv);
                } else if (which == 1) {
                    _Float16 hv = (_Float16)fv;
                    kh[idx] = hv;
                    kl[idx] = (_Float16)(fv - (float)hv);
                } else {
                    vt16[((size_t)(bhd * ND + dd)) * NN + nr] = (_Float16)fv;
                }
            }
        }
    }
}

// ---------------- fused quadratic-ReLU attention (split-precision QK^T) ----------------
// grid (8 q-tiles, 96 bh), 256 threads = 4 waves; wave handles 32 q-rows.
__global__ __launch_bounds__(256) void attn_kernel(
    const _Float16* __restrict__ qhp, const _Float16* __restrict__ qlp,
    const _Float16* __restrict__ khp, const _Float16* __restrict__ klp,
    const _Float16* __restrict__ vt16, _Float16* __restrict__ outh16,
    const float* __restrict__ alpha, const float* __restrict__ beta,
    const float* __restrict__ gamma)
{
    const int qt = blockIdx.x, bh = blockIdx.y;
    const int b = bh / NH, h = bh - b * NH;
    const int tid = threadIdx.x, lane = tid & 63, wv = tid >> 6;
    const int quad = lane >> 4, l16 = lane & 15;
    const float a2 = alpha[h] * 0.015625f;   // alpha * SCALE^2
    const float b1 = beta[h] * 0.125f;       // beta * SCALE
    const float g0 = gamma[h];

    __shared__ __align__(16) _Float16 sP[4][32 * 136];  // per-wave P, stride 136 (pad)

    const size_t qoff = ((size_t)(bh * NN + qt * 128)) * ND;
    const _Float16* Qh = qhp + qoff;
    const _Float16* Ql = qlp + qoff;
    const _Float16* Kh = khp + (size_t)bh * NN * ND;
    const _Float16* Kl = klp + (size_t)bh * NN * ND;
    const _Float16* Vb = vt16 + (size_t)bh * ND * NN;

    // Q fragments (hi and lo): 2 m-tiles x 2 k-steps
    f16x8 qfh[2][2], qfl[2][2];
#pragma unroll
    for (int mt = 0; mt < 2; mt++)
#pragma unroll
        for (int ks = 0; ks < 2; ks++) {
            size_t o = (size_t)(wv * 32 + mt * 16 + l16) * ND + ks * 32 + quad * 8;
            qfh[mt][ks] = *(const f16x8*)(Qh + o);
            qfl[mt][ks] = *(const f16x8*)(Ql + o);
        }

    f32x4 O[2][4] = {};
    float dsum[2][4] = {};

    for (int kt = 0; kt < 8; kt++) {
        // S = Q K^T (split: qh*kh + ql*kh + qh*kl), 32 x 128 per wave
        f32x4 S[2][8] = {};
#pragma unroll
        for (int nt = 0; nt < 8; nt++) {
#pragma unroll
            for (int ks = 0; ks < 2; ks++) {
                size_t o = (size_t)(kt * 128 + nt * 16 + l16) * ND + ks * 32 + quad * 8;
                f16x8 bhf = *(const f16x8*)(Kh + o);
                f16x8 blf = *(const f16x8*)(Kl + o);
#pragma unroll
                for (int mt = 0; mt < 2; mt++) {
                    S[mt][nt] = __builtin_amdgcn_mfma_f32_16x16x32_f16(qfh[mt][ks], bhf, S[mt][nt], 0, 0, 0);
                    S[mt][nt] = __builtin_amdgcn_mfma_f32_16x16x32_f16(qfl[mt][ks], bhf, S[mt][nt], 0, 0, 0);
                    S[mt][nt] = __builtin_amdgcn_mfma_f32_16x16x32_f16(qfh[mt][ks], blf, S[mt][nt], 0, 0, 0);
                }
            }
        }
        __syncthreads();  // prior PV reads of sP complete
        // w = relu(a2*s^2 + b1*s + g0); accumulate denom; P -> LDS fp16
#pragma unroll
        for (int mt = 0; mt < 2; mt++) {
#pragma unroll
            for (int nt = 0; nt < 8; nt++) {
#pragma unroll
                for (int r = 0; r < 4; r++) {
                    float s = S[mt][nt][r];
                    float w = fmaxf(a2 * s * s + b1 * s + g0, 0.f);
                    dsum[mt][r] += w;
                    sP[wv][(mt * 16 + quad * 4 + r) * 136 + nt * 16 + l16] = (_Float16)w;
                }
            }
        }
        __syncthreads();  // P writes visible
        // O += P * V : A = P (LDS), B = V^T (global, contiguous along kv index)
#pragma unroll
        for (int ks = 0; ks < 4; ks++) {
#pragma unroll
            for (int nt = 0; nt < 4; nt++) {
                f16x8 bfr = *(const f16x8*)(Vb + (size_t)(nt * 16 + l16) * NN + kt * 128 + ks * 32 + quad * 8);
#pragma unroll
                for (int mt = 0; mt < 2; mt++) {
                    f16x8 af = *(const f16x8*)(&sP[wv][(mt * 16 + l16) * 136 + ks * 32 + quad * 8]);
                    O[mt][nt] = __builtin_amdgcn_mfma_f32_16x16x32_f16(af, bfr, O[mt][nt], 0, 0, 0);
                }
            }
        }
    }

    // denominator: reduce across the 16 lanes of each quad-group
#pragma unroll
    for (int mt = 0; mt < 2; mt++)
#pragma unroll
        for (int r = 0; r < 4; r++) {
            float v = dsum[mt][r];
            v += __shfl_xor(v, 1);
            v += __shfl_xor(v, 2);
            v += __shfl_xor(v, 4);
            v += __shfl_xor(v, 8);
            dsum[mt][r] = 1.0f / (v + 1e-6f);
        }

    // normalize + store to outh16[B,N,H*d]
    const int base_row = qt * 128 + wv * 32;
#pragma unroll
    for (int mt = 0; mt < 2; mt++) {
#pragma unroll
        for (int nt = 0; nt < 4; nt++) {
#pragma unroll
            for (int r = 0; r < 4; r++) {
                float v = O[mt][nt][r] * dsum[mt][r];
                int row = base_row + mt * 16 + quad * 4 + r;  // token n
                int col = h * ND + nt * 16 + l16;             // channel c
                outh16[((size_t)(b * NN + row)) * NC + col] = (_Float16)v;
            }
        }
    }
}

// ---------------- proj GEMM: out[8192,768] = outh16 * wproj16^T + b_proj (fp32 out) ----------------
__global__ __launch_bounds__(256) void gemm_proj(
    const _Float16* __restrict__ A, const _Float16* __restrict__ Bw,
    const float* __restrict__ bias, float* __restrict__ out)
{
    __shared__ __align__(16) _Float16 sA[128 * 32];
    __shared__ __align__(16) _Float16 sB[128 * 32];
    const int tid = threadIdx.x;
    const int lane = tid & 63, wv = tid >> 6;
    const int quad = lane >> 4, l16 = lane & 15;
    const int wm = (wv >> 1) * 64, wn = (wv & 1) * 64;
    const int m0 = blockIdx.x * 128, n0 = blockIdx.y * 128;

    f32x4 acc[4][4] = {};

    for (int k0 = 0; k0 < NC; k0 += 32) {
#pragma unroll
        for (int i = 0; i < 2; i++) {
            int c = tid + i * 256;
            int r = c >> 2, kc = c & 3;
            uint4 va = *(const uint4*)(A + (size_t)(m0 + r) * NC + k0 + kc * 8);
            *(uint4*)(sA + c * 8) = va;
            uint4 vb = *(const uint4*)(Bw + (size_t)(n0 + r) * NC + k0 + kc * 8);
            *(uint4*)(sB + c * 8) = vb;
        }
        __syncthreads();
        f16x8 af[4], bf[4];
#pragma unroll
        for (int t = 0; t < 4; t++) {
            af[t] = *(const f16x8*)(sA + (wm + t * 16 + l16) * 32 + quad * 8);
            bf[t] = *(const f16x8*)(sB + (wn + t * 16 + l16) * 32 + quad * 8);
        }
#pragma unroll
        for (int i = 0; i < 4; i++)
#pragma unroll
            for (int j = 0; j < 4; j++)
                acc[i][j] = __builtin_amdgcn_mfma_f32_16x16x32_f16(af[i], bf[j], acc[i][j], 0, 0, 0);
        __syncthreads();
    }

#pragma unroll
    for (int i = 0; i < 4; i++) {
#pragma unroll
        for (int j = 0; j < 4; j++) {
#pragma unroll
            for (int r = 0; r < 4; r++) {
                int row = m0 + wm + i * 16 + quad * 4 + r;
                int col = n0 + wn + j * 16 + l16;
                out[(size_t)row * NC + col] = acc[i][j][r] + bias[col];
            }
        }
    }
}

// ---------------- launch ----------------
extern "C" void kernel_launch(void* const* d_in, const int* in_sizes, int n_in,
                              void* d_out, int out_size, void* d_ws, size_t ws_size,
                              hipStream_t stream) {
    const float* x      = (const float*)d_in[0];
    const float* w_qkv  = (const float*)d_in[1];
    const float* w_proj = (const float*)d_in[2];
    const float* b_proj = (const float*)d_in[3];
    const float* alpha  = (const float*)d_in[4];
    const float* beta   = (const float*)d_in[5];
    const float* gamma  = (const float*)d_in[6];
    float* out = (float*)d_out;

    char* ws = (char*)d_ws;
    // region 0 (0 .. 12.58 MB): wqkv hi/lo during gemm_qkv; reused as outh16 by attn
    _Float16* wqkvh  = (_Float16*)(ws + 0);            // 3,538,944 B
    _Float16* wqkvl  = (_Float16*)(ws + 3538944);      // 3,538,944 B
    _Float16* outh16 = (_Float16*)(ws + 0);            // 12,582,912 B (after gemm_qkv done)
    _Float16* qh     = (_Float16*)(ws + 12582912);     // 12,582,912 B
    _Float16* ql     = (_Float16*)(ws + 25165824);
    _Float16* kh     = (_Float16*)(ws + 37748736);
    _Float16* kl     = (_Float16*)(ws + 50331648);
    _Float16* vt16   = (_Float16*)(ws + 62914560);     // 12,582,912 B
    _Float16* wproj16= (_Float16*)(ws + 75497472);     // 1,179,648 B  (total ~76.7 MB)

    cvt_split_f32<<<1728, 256, 0, stream>>>(w_qkv, wqkvh, wqkvl, 442368);
    cvt_f32_f16<<<576, 256, 0, stream>>>(w_proj, wproj16, 147456);

    gemm_qkv<<<dim3(64, 18), 256, 0, stream>>>(x, wqkvh, wqkvl, qh, ql, kh, kl, vt16);
    attn_kernel<<<dim3(8, 96), 256, 0, stream>>>(qh, ql, kh, kl, vt16, outh16, alpha, beta, gamma);
    gemm_proj<<<dim3(64, 6), 256, 0, stream>>>(outh16, wproj16, b_proj, out);
}